// Round 1
// baseline (33248.502 us; speedup 1.0000x reference)
//
#include <hip/hip_runtime.h>
#include <cstdint>
#include <cstddef>

// Problem constants
// B=256, P=196, C=512, D=512, A=256, E=256, V=193, TC=256, T=255

__device__ __forceinline__ float sigf(float x){ return 1.f/(1.f + expf(-x)); }

// ---------------- sort (stable descending by length) ----------------
__global__ void k_sort(const int* cap_lens, int* si, int* dlw, float* out_dl, float* out_si){
  __shared__ int lens[256];
  int tid = threadIdx.x;
  lens[tid] = cap_lens[tid];
  __syncthreads();
  int L = lens[tid];
  int rank = 0;
  for (int j = 0; j < 256; ++j){
    int Lj = lens[j];
    rank += ((Lj > L) || (Lj == L && j < tid)) ? 1 : 0;
  }
  si[rank] = tid;
  dlw[rank] = L - 1;
  out_dl[rank] = (float)(L - 1);
  out_si[rank] = (float)tid;
}

// ---------------- caps gather ----------------
__global__ void k_caps(const int* caps, const int* si, int* caps_s, float* out_caps){
  int b = blockIdx.x, t = threadIdx.x;
  int v = caps[si[b]*256 + t];
  caps_s[b*256 + t] = v;
  out_caps[b*256 + t] = (float)v;
}

// ---------------- weight concatenation ----------------
struct ConcatP {
  const float *Wdec,*bdec,*Wfb,*bfb,*Wfc,*bfc,*Wih,*bih,*Whh,*bhh,*Winh,*binh,*Winc,*binc;
  float *Wcat0,*bcat0,*Wcat1,*bcat1,*Wcat3,*bcat3;
};
__global__ void k_concat(ConcatP p){
  int idx = blockIdx.x*blockDim.x + threadIdx.x;
  int stride = gridDim.x*blockDim.x;
  // Wcat0: [W_init_h ; W_init_c]  (1024 x 512)
  for (int i = idx; i < 1024*512; i += stride){
    int n = i >> 9, k = i & 511;
    p.Wcat0[i] = (n < 512) ? p.Winh[n*512 + k] : p.Winc[(n-512)*512 + k];
  }
  for (int i = idx; i < 1024; i += stride)
    p.bcat0[i] = (i < 512) ? p.binh[i] : p.binc[i-512];
  // Wcat1: [W_dec_att ; W_fbeta ; W_fc]  (961 x 512)
  for (int i = idx; i < 961*512; i += stride){
    int n = i >> 9, k = i & 511;
    p.Wcat1[i] = (n < 256) ? p.Wdec[n*512+k]
               : (n < 768) ? p.Wfb[(n-256)*512+k]
                           : p.Wfc[(n-768)*512+k];
  }
  for (int i = idx; i < 961; i += stride)
    p.bcat1[i] = (i < 256) ? p.bdec[i] : (i < 768) ? p.bfb[i-256] : p.bfc[i-768];
  // Wcat3: gate-interleaved [W_ih | W_hh]  (2048 x 1280), row n' = 4*j + g -> orig row g*512+j
  for (int i = idx; i < 2048*1280; i += stride){
    int n = i / 1280, k = i - n*1280;
    int j = n >> 2, g = n & 3, orow = g*512 + j;
    p.Wcat3[i] = (k < 768) ? p.Wih[orow*768 + k] : p.Whh[orow*512 + (k - 768)];
  }
  for (int i = idx; i < 2048; i += stride){
    int j = i >> 2, g = i & 3, orow = g*512 + j;
    p.bcat3[i] = p.bih[orow] + p.bhh[orow];
  }
}

// ---------------- mean of encoder rows (sorted order) ----------------
__global__ void k_mean(const float* enc, const int* si, float* mean_enc){
  int b = blockIdx.x, tid = threadIdx.x;
  const float* eb = enc + (size_t)si[b]*196*512;
  int cc = 2*tid;
  float s0 = 0.f, s1 = 0.f;
  #pragma unroll 4
  for (int pp = 0; pp < 196; ++pp){
    float2 v = *(const float2*)&eb[(size_t)pp*512 + cc];
    s0 += v.x; s1 += v.y;
  }
  mean_enc[b*512 + cc]     = s0 * (1.f/196.f);
  mean_enc[b*512 + cc + 1] = s1 * (1.f/196.f);
}

// ---------------- generic tiled GEMM: C = A(MxK) * B(NxK)^T, tile 32x64, thread 4x2 ----------------
// MODE 0: enc_att (plain +bias, out0 ldc=N, optional gathered A rows)
// MODE 1: init h/c split store (+bias)
// MODE 2: K1: dec_att / sigmoid gate / masked preds(t-1)
// MODE 3: K3: LSTM epilogue (gates interleaved i,f,g,o per unit)
struct GemmP {
  const float* A; const float* Bm; const float* bias;
  int M, N, K;
  int gatherA; const int* si;
  float* out0;
  float* dec_att; float* gatev; float* preds; const int* dl; int t;
  float* h; float* c;
};

template<int MODE>
__global__ __launch_bounds__(256,2) void k_gemm(GemmP p){
  __shared__ __align__(16) float smem[32*36 + 32*66];
  float* As = smem;            // [k][m], stride 36
  float* Bs = smem + 32*36;    // [k][n], stride 66
  const int tid = threadIdx.x;
  const int bn0 = blockIdx.x * 64;
  const int bm0 = blockIdx.y * 32;
  const int m0 = 4*(tid >> 5);
  const int n0 = 2*(tid & 31);
  float acc[4][2] = {{0.f,0.f},{0.f,0.f},{0.f,0.f},{0.f,0.f}};

  const int lm = tid >> 3;          // 0..31 (A tile row)
  const int k4 = (tid & 7) << 2;    // 0..28
  int gm_l = bm0 + lm;
  int arow = gm_l;
  if (p.gatherA) arow = p.si[gm_l / 196]*196 + (gm_l % 196);
  const float* Aptr = p.A + (size_t)arow * p.K + k4;

  for (int kt = 0; kt < p.K; kt += 32){
    float4 av = *(const float4*)(Aptr + kt);
    As[(k4+0)*36 + lm] = av.x;
    As[(k4+1)*36 + lm] = av.y;
    As[(k4+2)*36 + lm] = av.z;
    As[(k4+3)*36 + lm] = av.w;
    #pragma unroll
    for (int r = 0; r < 2; ++r){
      int idx = tid + r*256;
      int bn = idx >> 3;            // 0..63
      int bk = (idx & 7) << 2;      // 0..28
      int gn = bn0 + bn;
      float4 bv = make_float4(0.f,0.f,0.f,0.f);
      if (gn < p.N) bv = *(const float4*)(p.Bm + (size_t)gn * p.K + kt + bk);
      Bs[(bk+0)*66 + bn] = bv.x;
      Bs[(bk+1)*66 + bn] = bv.y;
      Bs[(bk+2)*66 + bn] = bv.z;
      Bs[(bk+3)*66 + bn] = bv.w;
    }
    __syncthreads();
    #pragma unroll
    for (int k = 0; k < 32; ++k){
      float4 a = *(const float4*)&As[k*36 + m0];
      float2 b = *(const float2*)&Bs[k*66 + n0];
      acc[0][0] += a.x*b.x; acc[0][1] += a.x*b.y;
      acc[1][0] += a.y*b.x; acc[1][1] += a.y*b.y;
      acc[2][0] += a.z*b.x; acc[2][1] += a.z*b.y;
      acc[3][0] += a.w*b.x; acc[3][1] += a.w*b.y;
    }
    __syncthreads();
  }

  if (MODE == 3){
    // stage biased gates tile to LDS, regroup (i,f,g,o) per unit, fused LSTM pointwise
    float* Cs = smem;  // 32 x 68
    #pragma unroll
    for (int i = 0; i < 4; ++i)
      #pragma unroll
      for (int j = 0; j < 2; ++j)
        Cs[(m0+i)*68 + n0 + j] = acc[i][j] + p.bias[bn0 + n0 + j];
    __syncthreads();
    #pragma unroll
    for (int r = 0; r < 2; ++r){
      int idx = tid + r*256;
      int m = idx >> 4, ju = idx & 15;
      float4 g4 = *(const float4*)&Cs[m*68 + 4*ju];
      int gm = bm0 + m;
      int gj = (bn0 >> 2) + ju;
      if (p.t < p.dl[gm]){
        float ig = sigf(g4.x), fg = sigf(g4.y);
        float gg = tanhf(g4.z), og = sigf(g4.w);
        float cn = fg * p.c[gm*512 + gj] + ig * gg;
        float hn = og * tanhf(cn);
        p.c[gm*512 + gj] = cn;
        p.h[gm*512 + gj] = hn;
      }
    }
  } else {
    #pragma unroll
    for (int i = 0; i < 4; ++i){
      int gm = bm0 + m0 + i;
      #pragma unroll
      for (int j = 0; j < 2; ++j){
        int gn = bn0 + n0 + j;
        if (gn >= p.N) continue;
        float v = acc[i][j] + p.bias[gn];
        if (MODE == 0){
          p.out0[(size_t)gm * p.N + gn] = v;
        } else if (MODE == 1){
          if (gn < 512) p.h[gm*512 + gn] = v;
          else          p.c[gm*512 + gn - 512] = v;
        } else { // MODE 2
          if (gn < 256)      p.dec_att[gm*256 + gn] = v;
          else if (gn < 768) p.gatev[gm*512 + gn - 256] = sigf(v);
          else {
            int tp = p.t - 1;
            if (tp >= 0)
              p.preds[((size_t)gm*255 + tp)*193 + (gn - 768)] = (tp < p.dl[gm]) ? v : 0.f;
          }
        }
      }
    }
  }
}

// ---------------- attention per batch element ----------------
struct AttnP {
  const float* enc_att; const float* enc; const int* si;
  const float* dec_att; const float* gatev;
  const float* wfull; const float* bfull;
  const float* emb; const int* caps_s;
  const float* h; float* z; float* alphas; const int* dl; int t;
};
__global__ __launch_bounds__(256) void k_attn(AttnP p){
  __shared__ __align__(16) float da[256];
  __shared__ __align__(16) float wfs[256];
  __shared__ __align__(16) float al[256];
  __shared__ float red[8];
  const int b = blockIdx.x, tid = threadIdx.x;
  da[tid]  = p.dec_att[b*256 + tid];
  wfs[tid] = p.wfull[tid];
  __syncthreads();
  float s = -1e30f;
  if (tid < 196){
    s = p.bfull[0];
    const float4* row = (const float4*)(p.enc_att + (size_t)b*196*256 + (size_t)tid*256);
    #pragma unroll 4
    for (int a4 = 0; a4 < 64; ++a4){
      float4 v = row[a4];
      float4 d = *(const float4*)&da[4*a4];
      float4 w = *(const float4*)&wfs[4*a4];
      s += fmaxf(v.x + d.x, 0.f)*w.x + fmaxf(v.y + d.y, 0.f)*w.y
         + fmaxf(v.z + d.z, 0.f)*w.z + fmaxf(v.w + d.w, 0.f)*w.w;
    }
  }
  // block max
  float mx = s;
  for (int o = 32; o > 0; o >>= 1) mx = fmaxf(mx, __shfl_down(mx, o, 64));
  const int wid = tid >> 6, lane = tid & 63;
  if (lane == 0) red[wid] = mx;
  __syncthreads();
  if (tid == 0) red[4] = fmaxf(fmaxf(red[0], red[1]), fmaxf(red[2], red[3]));
  __syncthreads();
  mx = red[4];
  float e = (tid < 196) ? expf(s - mx) : 0.f;
  float sm = e;
  for (int o = 32; o > 0; o >>= 1) sm += __shfl_down(sm, o, 64);
  if (lane == 0) red[wid] = sm;
  __syncthreads();
  if (tid == 0) red[5] = red[0] + red[1] + red[2] + red[3];
  __syncthreads();
  const float inv = 1.f / red[5];
  al[tid] = e * inv;
  __syncthreads();
  const int active = (p.t < p.dl[b]) ? 1 : 0;
  if (tid < 196)
    p.alphas[((size_t)b*255 + p.t)*196 + tid] = active ? al[tid] : 0.f;
  // awe = sum_p alpha[p] * enc[b,p,:]
  const float* eb = p.enc + (size_t)p.si[b]*196*512;
  const int cc = 2*tid;
  float v0 = 0.f, v1 = 0.f;
  #pragma unroll 4
  for (int pp = 0; pp < 196; ++pp){
    float a = al[pp];
    float2 e2 = *(const float2*)&eb[(size_t)pp*512 + cc];
    v0 += a * e2.x; v1 += a * e2.y;
  }
  float* zb = p.z + (size_t)b*1280;
  zb[256 + cc]     = p.gatev[b*512 + cc]     * v0;
  zb[256 + cc + 1] = p.gatev[b*512 + cc + 1] * v1;
  int tok = p.caps_s[b*256 + p.t];
  zb[tid] = p.emb[tok*256 + tid];
  zb[768 + cc]     = p.h[b*512 + cc];
  zb[768 + cc + 1] = p.h[b*512 + cc + 1];
}

extern "C" void kernel_launch(void* const* d_in, const int* in_sizes, int n_in,
                              void* d_out, int out_size, void* d_ws, size_t ws_size,
                              hipStream_t stream){
  (void)in_sizes; (void)n_in; (void)out_size; (void)ws_size;
  const float* enc   = (const float*)d_in[0];
  const int*   caps  = (const int*)d_in[1];
  const int*   clens = (const int*)d_in[2];
  const float* Wenc  = (const float*)d_in[3];
  const float* benc  = (const float*)d_in[4];
  const float* Wdec  = (const float*)d_in[5];
  const float* bdec  = (const float*)d_in[6];
  const float* Wfull = (const float*)d_in[7];
  const float* bfull = (const float*)d_in[8];
  const float* emb   = (const float*)d_in[9];
  const float* Wfc   = (const float*)d_in[10];
  const float* bfc   = (const float*)d_in[11];
  const float* Wih   = (const float*)d_in[12];
  const float* bih   = (const float*)d_in[13];
  const float* Whh   = (const float*)d_in[14];
  const float* bhh   = (const float*)d_in[15];
  const float* Winh  = (const float*)d_in[16];
  const float* binh  = (const float*)d_in[17];
  const float* Winc  = (const float*)d_in[18];
  const float* binc  = (const float*)d_in[19];
  const float* Wfb   = (const float*)d_in[20];
  const float* bfb   = (const float*)d_in[21];

  float* out       = (float*)d_out;
  float* out_preds = out;                  // 256*255*193
  float* out_caps  = out + 12599040;       // 256*256
  float* out_dl    = out + 12664576;       // 256
  float* out_alph  = out + 12664832;       // 256*255*196
  float* out_si    = out + 25459712;       // 256

  float* W = (float*)d_ws;
  int*   si      = (int*)W;                //      256
  int*   dlw     = si + 256;               //      256
  int*   caps_s  = dlw + 256;              //    65536
  float* mean_e  = (float*)(caps_s + 65536); // 131072
  float* h       = mean_e + 131072;        //   131072
  float* c       = h + 131072;             //   131072
  float* dec_att = c + 131072;             //    65536
  float* gatev   = dec_att + 65536;        //   131072
  float* z       = gatev + 131072;         //   327680
  float* Wcat0   = z + 327680;             //   524288
  float* bcat0   = Wcat0 + 524288;         //     1024
  float* Wcat1   = bcat0 + 1024;           //   492032
  float* bcat1   = Wcat1 + 492032;         //      964 (padded)
  float* Wcat3   = bcat1 + 964;            //  2621440
  float* bcat3   = Wcat3 + 2621440;        //     2048
  float* enc_att = bcat3 + 2048;           // 12845056  (total ~69.9 MB)

  k_sort<<<1, 256, 0, stream>>>(clens, si, dlw, out_dl, out_si);
  k_caps<<<256, 256, 0, stream>>>(caps, si, caps_s, out_caps);
  ConcatP cp{Wdec,bdec,Wfb,bfb,Wfc,bfc,Wih,bih,Whh,bhh,Winh,binh,Winc,binc,
             Wcat0,bcat0,Wcat1,bcat1,Wcat3,bcat3};
  k_concat<<<2048, 256, 0, stream>>>(cp);
  k_mean<<<256, 256, 0, stream>>>(enc, si, mean_e);

  { // h0 / c0
    GemmP g{};
    g.A = mean_e; g.Bm = Wcat0; g.bias = bcat0; g.M = 256; g.N = 1024; g.K = 512;
    g.gatherA = 0; g.si = si; g.h = h; g.c = c;
    k_gemm<1><<<dim3(16,8), 256, 0, stream>>>(g);
  }
  { // enc_att (gathered rows of encoder_output)
    GemmP g{};
    g.A = enc; g.Bm = Wenc; g.bias = benc; g.M = 50176; g.N = 256; g.K = 512;
    g.gatherA = 1; g.si = si; g.out0 = enc_att;
    k_gemm<0><<<dim3(4,1568), 256, 0, stream>>>(g);
  }

  for (int t = 0; t <= 255; ++t){
    { // K1: dec_att + gate + preds(t-1)
      GemmP g{};
      g.A = h; g.Bm = Wcat1; g.bias = bcat1; g.M = 256; g.N = 961; g.K = 512;
      g.gatherA = 0; g.si = si;
      g.dec_att = dec_att; g.gatev = gatev; g.preds = out_preds; g.dl = dlw; g.t = t;
      k_gemm<2><<<dim3(16,8), 256, 0, stream>>>(g);
    }
    if (t == 255) break;
    { // K2: attention + z build
      AttnP ap{enc_att, enc, si, dec_att, gatev, Wfull, bfull, emb, caps_s, h, z, out_alph, dlw, t};
      k_attn<<<256, 256, 0, stream>>>(ap);
    }
    { // K3: gates GEMM + fused LSTM pointwise
      GemmP g{};
      g.A = z; g.Bm = Wcat3; g.bias = bcat3; g.M = 256; g.N = 2048; g.K = 1280;
      g.gatherA = 0; g.si = si; g.dl = dlw; g.t = t; g.h = h; g.c = c;
      k_gemm<3><<<dim3(32,8), 256, 0, stream>>>(g);
    }
  }
}

// Round 2
// 16565.524 us; speedup vs baseline: 2.0071x; 2.0071x over previous
//
#include <hip/hip_runtime.h>
#include <cstdint>
#include <cstddef>

// B=256, P=196, C=512, D=512, A=256, E=256, V=193, TC=256, T=255

typedef unsigned short u16;
typedef unsigned int u32;
typedef __attribute__((ext_vector_type(8))) short short8;
typedef __attribute__((ext_vector_type(4))) float f32x4;

__device__ __forceinline__ float sigf(float x){ return 1.f/(1.f+expf(-x)); }
__device__ __forceinline__ u16 f2bf(float f){
  u32 u = __builtin_bit_cast(u32, f);
  u32 r = (u + 0x7fffu + ((u>>16)&1u)) >> 16;
  return (u16)r;
}
__device__ __forceinline__ float bf2f(u16 u){
  u32 x = ((u32)u) << 16;
  return __builtin_bit_cast(float, x);
}

// ---------------- sort (stable descending by length) ----------------
__global__ void k_sort(const int* cap_lens, int* si, int* dlw, float* out_dl, float* out_si){
  __shared__ int lens[256];
  int tid = threadIdx.x;
  lens[tid] = cap_lens[tid];
  __syncthreads();
  int L = lens[tid];
  int rank = 0;
  for (int j = 0; j < 256; ++j){
    int Lj = lens[j];
    rank += ((Lj > L) || (Lj == L && j < tid)) ? 1 : 0;
  }
  si[rank] = tid;
  dlw[rank] = L - 1;
  out_dl[rank] = (float)(L - 1);
  out_si[rank] = (float)tid;
}

// ---------------- caps gather ----------------
__global__ void k_caps(const int* caps, const int* si, int* caps_s, float* out_caps){
  int b = blockIdx.x, t = threadIdx.x;
  int v = caps[si[b]*256 + t];
  caps_s[b*256 + t] = v;
  out_caps[b*256 + t] = (float)v;
}

// ---------------- gather+convert encoder rows to bf16 (sorted order) ----------------
__global__ void k_prep(const float* enc, const int* si, u16* enc_sb){
  int b = blockIdx.x, tid = threadIdx.x;
  const float* src = enc + (size_t)si[b]*100352;   // 196*512
  u16* dst = enc_sb + (size_t)b*100352;
  for (int i = tid; i < 25088; i += 256){
    float4 v = *(const float4*)&src[i*4];
    ushort4 o;
    o.x = f2bf(v.x); o.y = f2bf(v.y); o.z = f2bf(v.z); o.w = f2bf(v.w);
    *(ushort4*)&dst[i*4] = o;
  }
}

// ---------------- mean of encoder rows (sorted order), bf16 out ----------------
__global__ void k_mean(const float* enc, const int* si, u16* mean_bf){
  int b = blockIdx.x, tid = threadIdx.x;
  const float* eb = enc + (size_t)si[b]*100352;
  int cc = 2*tid;
  float s0 = 0.f, s1 = 0.f;
  #pragma unroll 4
  for (int pp = 0; pp < 196; ++pp){
    float2 v = *(const float2*)&eb[(size_t)pp*512 + cc];
    s0 += v.x; s1 += v.y;
  }
  mean_bf[b*512 + cc]     = f2bf(s0 * (1.f/196.f));
  mean_bf[b*512 + cc + 1] = f2bf(s1 * (1.f/196.f));
}

// ---------------- weight concat + bf16 convert ----------------
struct ConcatP {
  const float *Wdec,*bdec,*Wfb,*bfb,*Wfc,*bfc,*Wih,*bih,*Whh,*bhh,*Winh,*binh,*Winc,*binc,*Wenc,*emb;
  u16 *Wc0,*Wc1,*Wc3,*Wenc_bf,*emb_bf;
  float *bc0,*bc1,*bc3;
};
__global__ void k_concat(ConcatP p){
  int idx = blockIdx.x*blockDim.x + threadIdx.x;
  int stride = gridDim.x*blockDim.x;
  // Wc0: [W_init_h ; W_init_c]  (1024 x 512) bf16
  for (int i = idx; i < 1024*512; i += stride){
    int n = i >> 9, k = i & 511;
    float v = (n < 512) ? p.Winh[n*512 + k] : p.Winc[(n-512)*512 + k];
    p.Wc0[i] = f2bf(v);
  }
  for (int i = idx; i < 1024; i += stride)
    p.bc0[i] = (i < 512) ? p.binh[i] : p.binc[i-512];
  // Wc1: [W_dec_att ; W_fbeta ; W_fc ; zero-pad]  (1024 x 512) bf16
  for (int i = idx; i < 1024*512; i += stride){
    int n = i >> 9, k = i & 511;
    float v = (n < 256) ? p.Wdec[n*512+k]
            : (n < 768) ? p.Wfb[(n-256)*512+k]
            : (n < 961) ? p.Wfc[(n-768)*512+k] : 0.f;
    p.Wc1[i] = f2bf(v);
  }
  for (int i = idx; i < 1024; i += stride)
    p.bc1[i] = (i < 256) ? p.bdec[i] : (i < 768) ? p.bfb[i-256] : (i < 961) ? p.bfc[i-768] : 0.f;
  // Wc3: gate-interleaved [W_ih | W_hh]  (2048 x 1280) bf16, row n' = 4*j+g -> orig row g*512+j
  for (int i = idx; i < 2048*1280; i += stride){
    int n = i / 1280, k = i - n*1280;
    int j = n >> 2, g = n & 3, orow = g*512 + j;
    float v = (k < 768) ? p.Wih[orow*768 + k] : p.Whh[orow*512 + (k - 768)];
    p.Wc3[i] = f2bf(v);
  }
  for (int i = idx; i < 2048; i += stride){
    int j = i >> 2, g = i & 3, orow = g*512 + j;
    p.bc3[i] = p.bih[orow] + p.bhh[orow];
  }
  // Wenc bf16 (256 x 512)
  for (int i = idx; i < 256*512; i += stride) p.Wenc_bf[i] = f2bf(p.Wenc[i]);
  // embedding bf16 (193 x 256)
  for (int i = idx; i < 193*256; i += stride) p.emb_bf[i] = f2bf(p.emb[i]);
}

// ---------------- bf16 MFMA GEMM: C(MxN) = A(MxK) * B(NxK)^T ----------------
// tile 64(M) x 128(N), BK=64; 4 waves, each 4 m-tiles x 2 n-tiles of 16x16x32 MFMA
// MODE 0: enc_att  -> bf16 out (+bias), ldc = N
// MODE 1: init     -> h_bf (n<512), c f32 (n>=512)
// MODE 2: K1       -> dec_att f32 / sigmoid gate f32 / masked preds (Nreal=961)
// MODE 3: K3       -> fused LSTM pointwise (gates interleaved i,f,g,o per unit)
struct MfmaP {
  const u16* A; const u16* Bw; const float* bias;
  int K, N;
  u16* out_bf;
  u16* h_bf; float* c;
  float* dec_att; float* gatev; float* preds; const int* dl; int t;
};

template<int MODE>
__global__ __launch_bounds__(256) void k_mfma(MfmaP p){
  __shared__ __align__(16) unsigned char smem[34048];
  u16* As = (u16*)smem;            // 64 x 64 bf16, xor-swizzled (8 KB)
  u16* Bs = (u16*)(smem + 8192);   // 128 x 64 bf16, xor-swizzled (16 KB)
  float* Cs = (float*)smem;        // MODE 3 epilogue: 64 x 132 f32 (33792 B)

  const int tid  = threadIdx.x;
  const int bn0  = blockIdx.x * 128;
  const int bm0  = blockIdx.y * 64;
  const int wave = tid >> 6;
  const int lane = tid & 63;
  const int ln   = lane & 15;
  const int quad = lane >> 4;

  f32x4 acc[4][2] = {};

  for (int k0 = 0; k0 < p.K; k0 += 64){
    // stage A: 64 rows x 8 granules(16B)
    #pragma unroll
    for (int r = 0; r < 2; ++r){
      int gl = r*256 + tid;
      int row = gl >> 3, gc = gl & 7;
      short8 v = *(const short8*)(p.A + (size_t)(bm0 + row)*p.K + k0 + gc*8);
      *(short8*)&As[row*64 + ((gc ^ (row & 7))<<3)] = v;
    }
    // stage B: 128 rows x 8 granules
    #pragma unroll
    for (int r = 0; r < 4; ++r){
      int gl = r*256 + tid;
      int row = gl >> 3, gc = gl & 7;
      short8 v = *(const short8*)(p.Bw + (size_t)(bn0 + row)*p.K + k0 + gc*8);
      *(short8*)&Bs[row*64 + ((gc ^ (row & 7))<<3)] = v;
    }
    __syncthreads();
    #pragma unroll
    for (int kk = 0; kk < 2; ++kk){
      short8 af[4], bfr[2];
      #pragma unroll
      for (int mt = 0; mt < 4; ++mt){
        int row = mt*16 + ln;
        int g = kk*4 + quad;
        af[mt] = *(const short8*)&As[row*64 + ((g ^ (row & 7))<<3)];
      }
      #pragma unroll
      for (int nt = 0; nt < 2; ++nt){
        int row = (wave*2 + nt)*16 + ln;
        int g = kk*4 + quad;
        bfr[nt] = *(const short8*)&Bs[row*64 + ((g ^ (row & 7))<<3)];
      }
      #pragma unroll
      for (int mt = 0; mt < 4; ++mt)
        #pragma unroll
        for (int nt = 0; nt < 2; ++nt)
          acc[mt][nt] = __builtin_amdgcn_mfma_f32_16x16x32_bf16(af[mt], bfr[nt], acc[mt][nt], 0, 0, 0);
    }
    __syncthreads();
  }

  if (MODE == 3){
    // gates tile -> LDS (+bias), regroup (i,f,g,o) quads, fused LSTM pointwise
    #pragma unroll
    for (int mt = 0; mt < 4; ++mt)
      #pragma unroll
      for (int nt = 0; nt < 2; ++nt){
        int n_loc = (wave*2 + nt)*16 + ln;
        float bv = p.bias[bn0 + n_loc];
        #pragma unroll
        for (int r = 0; r < 4; ++r)
          Cs[(mt*16 + quad*4 + r)*132 + n_loc] = acc[mt][nt][r] + bv;
      }
    __syncthreads();
    #pragma unroll
    for (int r = 0; r < 8; ++r){
      int idx = r*256 + tid;
      int m = idx >> 5, jl = idx & 31;
      float4 g4 = *(const float4*)&Cs[m*132 + jl*4];
      int gm = bm0 + m;
      int gj = (bn0 >> 2) + jl;
      if (p.t < p.dl[gm]){
        float ig = sigf(g4.x), fg = sigf(g4.y);
        float gg = tanhf(g4.z), og = sigf(g4.w);
        float cn = fg * p.c[gm*512 + gj] + ig * gg;
        float hn = og * tanhf(cn);
        p.c[gm*512 + gj] = cn;
        p.h_bf[gm*512 + gj] = f2bf(hn);
      }
    }
  } else {
    #pragma unroll
    for (int mt = 0; mt < 4; ++mt)
      #pragma unroll
      for (int nt = 0; nt < 2; ++nt){
        int n = bn0 + (wave*2 + nt)*16 + ln;
        float bv = p.bias[n];
        #pragma unroll
        for (int r = 0; r < 4; ++r){
          int m = bm0 + mt*16 + quad*4 + r;
          float v = acc[mt][nt][r] + bv;
          if (MODE == 0){
            p.out_bf[(size_t)m*p.N + n] = f2bf(v);
          } else if (MODE == 1){
            if (n < 512) p.h_bf[m*512 + n] = f2bf(v);
            else         p.c[m*512 + n - 512] = v;
          } else { // MODE 2
            if (n < 256)      p.dec_att[m*256 + n] = v;
            else if (n < 768) p.gatev[m*512 + n - 256] = sigf(v);
            else if (n < 961){
              int tp = p.t - 1;
              if (tp >= 0)
                p.preds[((size_t)m*255 + tp)*193 + (n - 768)] = (tp < p.dl[m]) ? v : 0.f;
            }
          }
        }
      }
  }
}

// ---------------- attention per batch element (bf16 streams) ----------------
struct AttnP {
  const u16* enc_att_bf; const u16* enc_sb;
  const float* dec_att; const float* gatev;
  const float* wfull; const float* bfull;
  const u16* emb_bf; const int* caps_s;
  const u16* h_bf; u16* z_bf; float* alphas; const int* dl; int t;
};
__global__ __launch_bounds__(256) void k_attn(AttnP p){
  __shared__ __align__(16) float da[256];
  __shared__ __align__(16) float wfs[256];
  __shared__ __align__(16) float al[256];
  __shared__ float red[8];
  const int b = blockIdx.x, tid = threadIdx.x;
  da[tid]  = p.dec_att[b*256 + tid];
  wfs[tid] = p.wfull[tid];
  __syncthreads();
  float s = -1e30f;
  if (tid < 196){
    s = p.bfull[0];
    const u16* row = p.enc_att_bf + ((size_t)b*196 + tid)*256;
    #pragma unroll 4
    for (int i = 0; i < 32; ++i){
      short8 v = *(const short8*)(row + i*8);
      const float* dd = &da[i*8];
      const float* ww = &wfs[i*8];
      #pragma unroll
      for (int j = 0; j < 8; ++j)
        s += fmaxf(bf2f((u16)v[j]) + dd[j], 0.f) * ww[j];
    }
  }
  float mx = s;
  for (int o = 32; o > 0; o >>= 1) mx = fmaxf(mx, __shfl_down(mx, o, 64));
  const int wid = tid >> 6, lane = tid & 63;
  if (lane == 0) red[wid] = mx;
  __syncthreads();
  if (tid == 0) red[4] = fmaxf(fmaxf(red[0], red[1]), fmaxf(red[2], red[3]));
  __syncthreads();
  mx = red[4];
  float e = (tid < 196) ? expf(s - mx) : 0.f;
  float sm = e;
  for (int o = 32; o > 0; o >>= 1) sm += __shfl_down(sm, o, 64);
  if (lane == 0) red[wid] = sm;
  __syncthreads();
  if (tid == 0) red[5] = red[0] + red[1] + red[2] + red[3];
  __syncthreads();
  const float inv = 1.f / red[5];
  al[tid] = e * inv;
  __syncthreads();
  const int active = (p.t < p.dl[b]) ? 1 : 0;
  if (tid < 196)
    p.alphas[((size_t)b*255 + p.t)*196 + tid] = active ? al[tid] : 0.f;
  // awe = sum_p alpha[p] * enc[b,p,:]   (bf16 enc)
  const u16* eb = p.enc_sb + (size_t)b*100352;
  const int cc = 2*tid;
  float v0 = 0.f, v1 = 0.f;
  #pragma unroll 4
  for (int pp = 0; pp < 196; ++pp){
    u32 u = *(const u32*)&eb[(size_t)pp*512 + cc];
    float a = al[pp];
    v0 += a * bf2f((u16)(u & 0xffffu));
    v1 += a * bf2f((u16)(u >> 16));
  }
  u16* zb = p.z_bf + (size_t)b*1280;
  zb[256 + cc]     = f2bf(p.gatev[b*512 + cc]     * v0);
  zb[256 + cc + 1] = f2bf(p.gatev[b*512 + cc + 1] * v1);
  int tok = p.caps_s[b*256 + p.t];
  zb[tid] = p.emb_bf[tok*256 + tid];
  *(u32*)&zb[768 + cc] = *(const u32*)&p.h_bf[b*512 + cc];
}

extern "C" void kernel_launch(void* const* d_in, const int* in_sizes, int n_in,
                              void* d_out, int out_size, void* d_ws, size_t ws_size,
                              hipStream_t stream){
  (void)in_sizes; (void)n_in; (void)out_size; (void)ws_size;
  const float* enc   = (const float*)d_in[0];
  const int*   caps  = (const int*)d_in[1];
  const int*   clens = (const int*)d_in[2];
  const float* Wenc  = (const float*)d_in[3];
  const float* benc  = (const float*)d_in[4];
  const float* Wdec  = (const float*)d_in[5];
  const float* bdec  = (const float*)d_in[6];
  const float* Wfull = (const float*)d_in[7];
  const float* bfull = (const float*)d_in[8];
  const float* emb   = (const float*)d_in[9];
  const float* Wfc   = (const float*)d_in[10];
  const float* bfc   = (const float*)d_in[11];
  const float* Wih   = (const float*)d_in[12];
  const float* bih   = (const float*)d_in[13];
  const float* Whh   = (const float*)d_in[14];
  const float* bhh   = (const float*)d_in[15];
  const float* Winh  = (const float*)d_in[16];
  const float* binh  = (const float*)d_in[17];
  const float* Winc  = (const float*)d_in[18];
  const float* binc  = (const float*)d_in[19];
  const float* Wfb   = (const float*)d_in[20];
  const float* bfb   = (const float*)d_in[21];

  float* out       = (float*)d_out;
  float* out_preds = out;                  // 256*255*193
  float* out_caps  = out + 12599040;       // 256*256
  float* out_dl    = out + 12664576;       // 256
  float* out_alph  = out + 12664832;       // 256*255*196
  float* out_si    = out + 25459712;       // 256

  // workspace layout (bytes, 256-aligned chunks)
  char* w = (char*)d_ws;
  size_t off = 0;
  auto alloc = [&](size_t bytes) -> void* {
    void* pp = w + off; off += (bytes + 255) & ~(size_t)255; return pp;
  };
  int*   si      = (int*)  alloc(256*4);
  int*   dlw     = (int*)  alloc(256*4);
  int*   caps_s  = (int*)  alloc(65536*4);
  float* c       = (float*)alloc(131072*4);
  float* dec_att = (float*)alloc(65536*4);
  float* gatev   = (float*)alloc(131072*4);
  float* bc0     = (float*)alloc(1024*4);
  float* bc1     = (float*)alloc(1024*4);
  float* bc3     = (float*)alloc(2048*4);
  u16*   mean_bf = (u16*)  alloc(131072*2);
  u16*   h_bf    = (u16*)  alloc(131072*2);
  u16*   z_bf    = (u16*)  alloc(327680*2);
  u16*   Wc0     = (u16*)  alloc(524288*2);
  u16*   Wc1     = (u16*)  alloc(524288*2);
  u16*   Wc3     = (u16*)  alloc(2621440*2);
  u16*   Wenc_bf = (u16*)  alloc(131072*2);
  u16*   emb_bf  = (u16*)  alloc(49408*2);
  u16*   enc_sb  = (u16*)  alloc(25690112ull*2);   // 256 x 196 x 512 bf16
  u16*   enc_att = (u16*)  alloc(12845056ull*2);   // 50176 x 256 bf16

  k_sort<<<1, 256, 0, stream>>>(clens, si, dlw, out_dl, out_si);
  k_caps<<<256, 256, 0, stream>>>(caps, si, caps_s, out_caps);
  k_prep<<<256, 256, 0, stream>>>(enc, si, enc_sb);
  k_mean<<<256, 256, 0, stream>>>(enc, si, mean_bf);
  ConcatP cp{Wdec,bdec,Wfb,bfb,Wfc,bfc,Wih,bih,Whh,bhh,Winh,binh,Winc,binc,Wenc,emb,
             Wc0,Wc1,Wc3,Wenc_bf,emb_bf,bc0,bc1,bc3};
  k_concat<<<2048, 256, 0, stream>>>(cp);

  { // h0 / c0 : M=256, N=1024, K=512
    MfmaP g{};
    g.A = mean_bf; g.Bw = Wc0; g.bias = bc0; g.K = 512; g.N = 1024;
    g.h_bf = h_bf; g.c = c;
    k_mfma<1><<<dim3(8,4), 256, 0, stream>>>(g);
  }
  { // enc_att : M=50176, N=256, K=512, bf16 out
    MfmaP g{};
    g.A = enc_sb; g.Bw = Wenc_bf; g.bias = benc; g.K = 512; g.N = 256;
    g.out_bf = enc_att;
    k_mfma<0><<<dim3(2,784), 256, 0, stream>>>(g);
  }

  for (int t = 0; t <= 255; ++t){
    { // K1: dec_att + gate + preds(t-1) : M=256, N=1024(pad of 961), K=512
      MfmaP g{};
      g.A = h_bf; g.Bw = Wc1; g.bias = bc1; g.K = 512; g.N = 1024;
      g.dec_att = dec_att; g.gatev = gatev; g.preds = out_preds; g.dl = dlw; g.t = t;
      k_mfma<2><<<dim3(8,4), 256, 0, stream>>>(g);
    }
    if (t == 255) break;
    { // K2: attention + z build
      AttnP ap{enc_att, enc_sb, dec_att, gatev, Wfull, bfull, emb_bf, caps_s,
               h_bf, z_bf, out_alph, dlw, t};
      k_attn<<<256, 256, 0, stream>>>(ap);
    }
    { // K3: gates GEMM + fused LSTM : M=256, N=2048, K=1280
      MfmaP g{};
      g.A = z_bf; g.Bw = Wc3; g.bias = bc3; g.K = 1280; g.N = 2048;
      g.dl = dlw; g.t = t; g.h_bf = h_bf; g.c = c;
      k_mfma<3><<<dim3(16,4), 256, 0, stream>>>(g);
    }
  }
}

// Round 3
// 11992.738 us; speedup vs baseline: 2.7724x; 1.3813x over previous
//
#include <hip/hip_runtime.h>
#include <cstdint>
#include <cstddef>

// B=256, P=196, C=512, D=512, A=256, E=256, V=193, TC=256, T=255

typedef unsigned short u16;
typedef unsigned int u32;
typedef __attribute__((ext_vector_type(8))) short short8;
typedef __attribute__((ext_vector_type(4))) float f32x4;

__device__ __forceinline__ float sigf(float x){ return 1.f/(1.f+expf(-x)); }
__device__ __forceinline__ u16 f2bf(float f){
  u32 u = __builtin_bit_cast(u32, f);
  u32 r = (u + 0x7fffu + ((u>>16)&1u)) >> 16;
  return (u16)r;
}
__device__ __forceinline__ float bf2f(u16 u){
  u32 x = ((u32)u) << 16;
  return __builtin_bit_cast(float, x);
}

// ---------------- zero preds/alphas (harness poisons d_out every launch) ----------------
__global__ void k_zero(float* a, int na4, float* b, int nb4){
  int i = blockIdx.x*blockDim.x + threadIdx.x;
  int stride = gridDim.x*blockDim.x;
  float4 z = make_float4(0.f,0.f,0.f,0.f);
  for (int j = i; j < na4; j += stride) ((float4*)a)[j] = z;
  for (int j = i; j < nb4; j += stride) ((float4*)b)[j] = z;
}

// ---------------- sort (stable descending by length) ----------------
__global__ void k_sort(const int* cap_lens, int* si, int* dlw, float* out_dl, float* out_si){
  __shared__ int lens[256];
  int tid = threadIdx.x;
  lens[tid] = cap_lens[tid];
  __syncthreads();
  int L = lens[tid];
  int rank = 0;
  for (int j = 0; j < 256; ++j){
    int Lj = lens[j];
    rank += ((Lj > L) || (Lj == L && j < tid)) ? 1 : 0;
  }
  si[rank] = tid;
  dlw[rank] = L - 1;
  out_dl[rank] = (float)(L - 1);
  out_si[rank] = (float)tid;
}

// ---------------- caps gather ----------------
__global__ void k_caps(const int* caps, const int* si, int* caps_s, float* out_caps){
  int b = blockIdx.x, t = threadIdx.x;
  int v = caps[si[b]*256 + t];
  caps_s[b*256 + t] = v;
  out_caps[b*256 + t] = (float)v;
}

// ---------------- gather+convert encoder rows to bf16 (sorted order) ----------------
__global__ void k_prep(const float* enc, const int* si, u16* enc_sb){
  int b = blockIdx.x, tid = threadIdx.x;
  const float* src = enc + (size_t)si[b]*100352;   // 196*512
  u16* dst = enc_sb + (size_t)b*100352;
  for (int i = tid; i < 25088; i += 256){
    float4 v = *(const float4*)&src[i*4];
    ushort4 o;
    o.x = f2bf(v.x); o.y = f2bf(v.y); o.z = f2bf(v.z); o.w = f2bf(v.w);
    *(ushort4*)&dst[i*4] = o;
  }
}

// ---------------- mean of encoder rows (sorted order), bf16 out ----------------
__global__ void k_mean(const float* enc, const int* si, u16* mean_bf){
  int b = blockIdx.x, tid = threadIdx.x;
  const float* eb = enc + (size_t)si[b]*100352;
  int cc = 2*tid;
  float s0 = 0.f, s1 = 0.f;
  #pragma unroll 4
  for (int pp = 0; pp < 196; ++pp){
    float2 v = *(const float2*)&eb[(size_t)pp*512 + cc];
    s0 += v.x; s1 += v.y;
  }
  mean_bf[b*512 + cc]     = f2bf(s0 * (1.f/196.f));
  mean_bf[b*512 + cc + 1] = f2bf(s1 * (1.f/196.f));
}

// ---------------- weight concat + bf16 convert ----------------
struct ConcatP {
  const float *Wdec,*bdec,*Wfb,*bfb,*Wfc,*bfc,*Wih,*bih,*Whh,*bhh,*Winh,*binh,*Winc,*binc,*Wenc,*emb;
  u16 *Wc0,*Wc1,*Wc3,*Wenc_bf,*emb_bf;
  float *bc0,*bc1,*bc3;
};
__global__ void k_concat(ConcatP p){
  int idx = blockIdx.x*blockDim.x + threadIdx.x;
  int stride = gridDim.x*blockDim.x;
  for (int i = idx; i < 1024*512; i += stride){
    int n = i >> 9, k = i & 511;
    float v = (n < 512) ? p.Winh[n*512 + k] : p.Winc[(n-512)*512 + k];
    p.Wc0[i] = f2bf(v);
  }
  for (int i = idx; i < 1024; i += stride)
    p.bc0[i] = (i < 512) ? p.binh[i] : p.binc[i-512];
  for (int i = idx; i < 1024*512; i += stride){
    int n = i >> 9, k = i & 511;
    float v = (n < 256) ? p.Wdec[n*512+k]
            : (n < 768) ? p.Wfb[(n-256)*512+k]
            : (n < 961) ? p.Wfc[(n-768)*512+k] : 0.f;
    p.Wc1[i] = f2bf(v);
  }
  for (int i = idx; i < 1024; i += stride)
    p.bc1[i] = (i < 256) ? p.bdec[i] : (i < 768) ? p.bfb[i-256] : (i < 961) ? p.bfc[i-768] : 0.f;
  // Wc3: gate-interleaved [W_ih | W_hh] (2048 x 1280), row n'=4*j+g -> orig row g*512+j
  for (int i = idx; i < 2048*1280; i += stride){
    int n = i / 1280, k = i - n*1280;
    int j = n >> 2, g = n & 3, orow = g*512 + j;
    float v = (k < 768) ? p.Wih[orow*768 + k] : p.Whh[orow*512 + (k - 768)];
    p.Wc3[i] = f2bf(v);
  }
  for (int i = idx; i < 2048; i += stride){
    int j = i >> 2, g = i & 3, orow = g*512 + j;
    p.bc3[i] = p.bih[orow] + p.bhh[orow];
  }
  for (int i = idx; i < 256*512; i += stride) p.Wenc_bf[i] = f2bf(p.Wenc[i]);
  for (int i = idx; i < 193*256; i += stride) p.emb_bf[i] = f2bf(p.emb[i]);
}

// ---------------- bf16 MFMA GEMM, double-buffered: C(MxN) = A(MxK)*B(NxK)^T ----------------
// tile 64(M) x 64*NT(N), BK=64; 4 waves, each 4 m-tiles x NT n-tiles of 16x16x32
// MODE 0: enc_att -> bf16 (+bias);  MODE 1: init h/c;  MODE 2: K1 (skip if dl[bm0] < t)
// MODE 3: K3 fused LSTM (skip if dl[bm0] <= t)
struct MfmaP {
  const u16* A; const u16* Bw; const float* bias;
  int K, N;
  u16* out_bf;
  u16* h_bf; float* c;
  float* dec_att; float* gatev; float* preds; const int* dl; int t;
};

template<int MODE, int NT>
__global__ __launch_bounds__(256) void k_mfma(MfmaP p){
  __shared__ __align__(16) unsigned char smem[16384 + 16384*NT];
  u16* As0 = (u16*)smem;                 // [2][64*64]
  u16* Bs0 = (u16*)(smem + 16384);       // [2][64*64*NT]
  float* Cs = (float*)smem;              // MODE 3 epilogue overlay: 64 x 68 f32

  const int tid  = threadIdx.x;
  const int bn0  = blockIdx.x * 64 * NT;
  const int bm0  = blockIdx.y * 64;
  const int wave = tid >> 6;
  const int lane = tid & 63;
  const int ln   = lane & 15;
  const int quad = lane >> 4;

  if (MODE == 2){ if (p.dl[bm0] <  p.t) return; }
  if (MODE == 3){ if (p.dl[bm0] <= p.t) return; }

  f32x4 acc[4][NT] = {};
  short8 pa[2], pb[2*NT];

  const int srow = tid >> 3;          // 0..31
  const int sgc  = tid & 7;           // granule col 0..7

  // prefetch k0=0
  #pragma unroll
  for (int r = 0; r < 2; ++r)
    pa[r] = *(const short8*)(p.A + (size_t)(bm0 + srow + 32*r)*p.K + sgc*8);
  #pragma unroll
  for (int r = 0; r < 2*NT; ++r)
    pb[r] = *(const short8*)(p.Bw + (size_t)(bn0 + srow + 32*r)*p.K + sgc*8);
  // store buf 0
  #pragma unroll
  for (int r = 0; r < 2; ++r){
    int row = srow + 32*r;
    *(short8*)&As0[row*64 + ((sgc ^ (row & 7))<<3)] = pa[r];
  }
  #pragma unroll
  for (int r = 0; r < 2*NT; ++r){
    int row = srow + 32*r;
    *(short8*)&Bs0[row*64 + ((sgc ^ (row & 7))<<3)] = pb[r];
  }

  const int nIter = p.K >> 6;
  int ib = 0;
  for (int it = 0; ; ){
    __syncthreads();
    const bool more = (it + 1 < nIter);
    if (more){
      int k0 = (it + 1) << 6;
      #pragma unroll
      for (int r = 0; r < 2; ++r)
        pa[r] = *(const short8*)(p.A + (size_t)(bm0 + srow + 32*r)*p.K + k0 + sgc*8);
      #pragma unroll
      for (int r = 0; r < 2*NT; ++r)
        pb[r] = *(const short8*)(p.Bw + (size_t)(bn0 + srow + 32*r)*p.K + k0 + sgc*8);
    }
    const u16* As = &As0[ib*4096];
    const u16* Bs = &Bs0[ib*4096*NT];
    #pragma unroll
    for (int kk = 0; kk < 2; ++kk){
      short8 af[4], bfr[NT];
      #pragma unroll
      for (int mt = 0; mt < 4; ++mt){
        int row = mt*16 + ln;
        int g = kk*4 + quad;
        af[mt] = *(const short8*)&As[row*64 + ((g ^ (row & 7))<<3)];
      }
      #pragma unroll
      for (int nt = 0; nt < NT; ++nt){
        int row = (wave*NT + nt)*16 + ln;
        int g = kk*4 + quad;
        bfr[nt] = *(const short8*)&Bs[row*64 + ((g ^ (row & 7))<<3)];
      }
      #pragma unroll
      for (int mt = 0; mt < 4; ++mt)
        #pragma unroll
        for (int nt = 0; nt < NT; ++nt)
          acc[mt][nt] = __builtin_amdgcn_mfma_f32_16x16x32_bf16(af[mt], bfr[nt], acc[mt][nt], 0, 0, 0);
    }
    if (!more) break;
    ib ^= 1;
    u16* Aw = &As0[ib*4096];
    u16* Bww = &Bs0[ib*4096*NT];
    #pragma unroll
    for (int r = 0; r < 2; ++r){
      int row = srow + 32*r;
      *(short8*)&Aw[row*64 + ((sgc ^ (row & 7))<<3)] = pa[r];
    }
    #pragma unroll
    for (int r = 0; r < 2*NT; ++r){
      int row = srow + 32*r;
      *(short8*)&Bww[row*64 + ((sgc ^ (row & 7))<<3)] = pb[r];
    }
    ++it;
  }

  if (MODE == 3){
    // gates tile -> LDS (+bias), regroup (i,f,g,o) quads, fused LSTM pointwise
    __syncthreads();
    {
      int n_loc = wave*16 + ln;     // NT==1
      float bv = p.bias[bn0 + n_loc];
      #pragma unroll
      for (int mt = 0; mt < 4; ++mt)
        #pragma unroll
        for (int r = 0; r < 4; ++r)
          Cs[(mt*16 + quad*4 + r)*68 + n_loc] = acc[mt][0][r] + bv;
    }
    __syncthreads();
    #pragma unroll
    for (int r = 0; r < 4; ++r){
      int idx = r*256 + tid;          // 64 rows x 16 unit-quads
      int m = idx >> 4, jl = idx & 15;
      float4 g4 = *(const float4*)&Cs[m*68 + jl*4];
      int gm = bm0 + m;
      int gj = (bn0 >> 2) + jl;
      if (p.t < p.dl[gm]){
        float ig = sigf(g4.x), fg = sigf(g4.y);
        float gg = tanhf(g4.z), og = sigf(g4.w);
        float cn = fg * p.c[gm*512 + gj] + ig * gg;
        float hn = og * tanhf(cn);
        p.c[gm*512 + gj] = cn;
        p.h_bf[gm*512 + gj] = f2bf(hn);
      }
    }
  } else {
    #pragma unroll
    for (int nt = 0; nt < NT; ++nt){
      int n = bn0 + (wave*NT + nt)*16 + ln;
      float bv = p.bias[n];
      #pragma unroll
      for (int mt = 0; mt < 4; ++mt)
        #pragma unroll
        for (int r = 0; r < 4; ++r){
          int m = bm0 + mt*16 + quad*4 + r;
          float v = acc[mt][nt][r] + bv;
          if (MODE == 0){
            p.out_bf[(size_t)m*p.N + n] = f2bf(v);
          } else if (MODE == 1){
            if (n < 512) p.h_bf[m*512 + n] = f2bf(v);
            else         p.c[m*512 + n - 512] = v;
          } else { // MODE 2
            if (n < 256)      p.dec_att[m*256 + n] = v;
            else if (n < 768) p.gatev[m*512 + n - 256] = sigf(v);
            else if (n < 961){
              int tp = p.t - 1;
              if (tp >= 0)
                p.preds[((size_t)m*255 + tp)*193 + (n - 768)] = (tp < p.dl[m]) ? v : 0.f;
            }
          }
        }
    }
  }
}

// ---------------- attention per batch element (bf16 streams) ----------------
struct AttnP {
  const u16* enc_att_bf; const u16* enc_sb;
  const float* dec_att; const float* gatev;
  const float* wfull; const float* bfull;
  const u16* emb_bf; const int* caps_s;
  const u16* h_bf; u16* z_bf; float* alphas; const int* dl; int t;
};
__global__ __launch_bounds__(256) void k_attn(AttnP p){
  __shared__ __align__(16) float da[256];
  __shared__ __align__(16) float wfs[256];
  __shared__ __align__(16) float al[256];
  __shared__ float red[8];
  const int b = blockIdx.x, tid = threadIdx.x;
  if (p.t >= p.dl[b]) return;      // inactive: alphas pre-zeroed, h/c/z untouched
  da[tid]  = p.dec_att[b*256 + tid];
  wfs[tid] = p.wfull[tid];
  __syncthreads();
  float s = -1e30f;
  if (tid < 196){
    s = p.bfull[0];
    const u16* row = p.enc_att_bf + ((size_t)b*196 + tid)*256;
    #pragma unroll 4
    for (int i = 0; i < 32; ++i){
      short8 v = *(const short8*)(row + i*8);
      const float* dd = &da[i*8];
      const float* ww = &wfs[i*8];
      #pragma unroll
      for (int j = 0; j < 8; ++j)
        s += fmaxf(bf2f((u16)v[j]) + dd[j], 0.f) * ww[j];
    }
  }
  float mx = s;
  for (int o = 32; o > 0; o >>= 1) mx = fmaxf(mx, __shfl_down(mx, o, 64));
  const int wid = tid >> 6, lane = tid & 63;
  if (lane == 0) red[wid] = mx;
  __syncthreads();
  if (tid == 0) red[4] = fmaxf(fmaxf(red[0], red[1]), fmaxf(red[2], red[3]));
  __syncthreads();
  mx = red[4];
  float e = (tid < 196) ? expf(s - mx) : 0.f;
  float sm = e;
  for (int o = 32; o > 0; o >>= 1) sm += __shfl_down(sm, o, 64);
  if (lane == 0) red[wid] = sm;
  __syncthreads();
  if (tid == 0) red[5] = red[0] + red[1] + red[2] + red[3];
  __syncthreads();
  const float inv = 1.f / red[5];
  al[tid] = e * inv;
  __syncthreads();
  if (tid < 196)
    p.alphas[((size_t)b*255 + p.t)*196 + tid] = al[tid];
  // awe = sum_p alpha[p] * enc[b,p,:]
  const u16* eb = p.enc_sb + (size_t)b*100352;
  const int cc = 2*tid;
  float v0 = 0.f, v1 = 0.f;
  #pragma unroll 4
  for (int pp = 0; pp < 196; ++pp){
    u32 u = *(const u32*)&eb[(size_t)pp*512 + cc];
    float a = al[pp];
    v0 += a * bf2f((u16)(u & 0xffffu));
    v1 += a * bf2f((u16)(u >> 16));
  }
  u16* zb = p.z_bf + (size_t)b*1280;
  zb[256 + cc]     = f2bf(p.gatev[b*512 + cc]     * v0);
  zb[256 + cc + 1] = f2bf(p.gatev[b*512 + cc + 1] * v1);
  int tok = p.caps_s[b*256 + p.t];
  zb[tid] = p.emb_bf[tok*256 + tid];
  *(u32*)&zb[768 + cc] = *(const u32*)&p.h_bf[b*512 + cc];
}

extern "C" void kernel_launch(void* const* d_in, const int* in_sizes, int n_in,
                              void* d_out, int out_size, void* d_ws, size_t ws_size,
                              hipStream_t stream){
  (void)in_sizes; (void)n_in; (void)out_size; (void)ws_size;
  const float* enc   = (const float*)d_in[0];
  const int*   caps  = (const int*)d_in[1];
  const int*   clens = (const int*)d_in[2];
  const float* Wenc  = (const float*)d_in[3];
  const float* benc  = (const float*)d_in[4];
  const float* Wdec  = (const float*)d_in[5];
  const float* bdec  = (const float*)d_in[6];
  const float* Wfull = (const float*)d_in[7];
  const float* bfull = (const float*)d_in[8];
  const float* emb   = (const float*)d_in[9];
  const float* Wfc   = (const float*)d_in[10];
  const float* bfc   = (const float*)d_in[11];
  const float* Wih   = (const float*)d_in[12];
  const float* bih   = (const float*)d_in[13];
  const float* Whh   = (const float*)d_in[14];
  const float* bhh   = (const float*)d_in[15];
  const float* Winh  = (const float*)d_in[16];
  const float* binh  = (const float*)d_in[17];
  const float* Winc  = (const float*)d_in[18];
  const float* binc  = (const float*)d_in[19];
  const float* Wfb   = (const float*)d_in[20];
  const float* bfb   = (const float*)d_in[21];

  float* out       = (float*)d_out;
  float* out_preds = out;                  // 256*255*193
  float* out_caps  = out + 12599040;       // 256*256
  float* out_dl    = out + 12664576;       // 256
  float* out_alph  = out + 12664832;       // 256*255*196
  float* out_si    = out + 25459712;       // 256

  char* w = (char*)d_ws;
  size_t off = 0;
  auto alloc = [&](size_t bytes) -> void* {
    void* pp = w + off; off += (bytes + 255) & ~(size_t)255; return pp;
  };
  int*   si      = (int*)  alloc(256*4);
  int*   dlw     = (int*)  alloc(256*4);
  int*   caps_s  = (int*)  alloc(65536*4);
  float* c       = (float*)alloc(131072*4);
  float* dec_att = (float*)alloc(65536*4);
  float* gatev   = (float*)alloc(131072*4);
  float* bc0     = (float*)alloc(1024*4);
  float* bc1     = (float*)alloc(1024*4);
  float* bc3     = (float*)alloc(2048*4);
  u16*   mean_bf = (u16*)  alloc(131072*2);
  u16*   h_bf    = (u16*)  alloc(131072*2);
  u16*   z_bf    = (u16*)  alloc(327680*2);
  u16*   Wc0     = (u16*)  alloc(524288*2);
  u16*   Wc1     = (u16*)  alloc(524288*2);
  u16*   Wc3     = (u16*)  alloc(2621440*2);
  u16*   Wenc_bf = (u16*)  alloc(131072*2);
  u16*   emb_bf  = (u16*)  alloc(49408*2);
  u16*   enc_sb  = (u16*)  alloc(25690112ull*2);   // 256 x 196 x 512 bf16
  u16*   enc_att = (u16*)  alloc(12845056ull*2);   // 50176 x 256 bf16

  k_zero<<<1024, 256, 0, stream>>>(out_preds, 12599040/4, out_alph, 12794880/4);
  k_sort<<<1, 256, 0, stream>>>(clens, si, dlw, out_dl, out_si);
  k_caps<<<256, 256, 0, stream>>>(caps, si, caps_s, out_caps);
  k_prep<<<256, 256, 0, stream>>>(enc, si, enc_sb);
  k_mean<<<256, 256, 0, stream>>>(enc, si, mean_bf);
  ConcatP cp{Wdec,bdec,Wfb,bfb,Wfc,bfc,Wih,bih,Whh,bhh,Winh,binh,Winc,binc,Wenc,emb,
             Wc0,Wc1,Wc3,Wenc_bf,emb_bf,bc0,bc1,bc3};
  k_concat<<<2048, 256, 0, stream>>>(cp);

  { // h0 / c0 : M=256, N=1024, K=512
    MfmaP g{};
    g.A = mean_bf; g.Bw = Wc0; g.bias = bc0; g.K = 512; g.N = 1024;
    g.h_bf = h_bf; g.c = c;
    k_mfma<1,1><<<dim3(16,4), 256, 0, stream>>>(g);
  }
  { // enc_att : M=50176, N=256, K=512, bf16 out
    MfmaP g{};
    g.A = enc_sb; g.Bw = Wenc_bf; g.bias = benc; g.K = 512; g.N = 256;
    g.out_bf = enc_att;
    k_mfma<0,2><<<dim3(2,784), 256, 0, stream>>>(g);
  }

  for (int t = 0; t <= 255; ++t){
    { // K1: dec_att + gate + preds(t-1) : M=256, N=1024(pad of 961), K=512
      MfmaP g{};
      g.A = h_bf; g.Bw = Wc1; g.bias = bc1; g.K = 512; g.N = 1024;
      g.dec_att = dec_att; g.gatev = gatev; g.preds = out_preds; g.dl = dlw; g.t = t;
      k_mfma<2,1><<<dim3(16,4), 256, 0, stream>>>(g);
    }
    if (t == 255) break;
    { // K2: attention + z build
      AttnP ap{enc_att, enc_sb, dec_att, gatev, Wfull, bfull, emb_bf, caps_s,
               h_bf, z_bf, out_alph, dlw, t};
      k_attn<<<256, 256, 0, stream>>>(ap);
    }
    { // K3: gates GEMM + fused LSTM : M=256, N=2048, K=1280
      MfmaP g{};
      g.A = z_bf; g.Bw = Wc3; g.bias = bc3; g.K = 1280; g.N = 2048;
      g.dl = dlw; g.t = t; g.h_bf = h_bf; g.c = c;
      k_mfma<3,1><<<dim3(32,4), 256, 0, stream>>>(g);
    }
  }
}